// Round 3
// baseline (135.325 us; speedup 1.0000x reference)
//
#include <hip/hip_runtime.h>

#define Tn 512
#define Bn 32768

typedef float f32x4 __attribute__((ext_vector_type(4)));

// One thread per neuron b. Sequential T-loop (carry dependence), double-buffered
// 16-step input prefetch (64 loads/buffer, pins vmcnt near its 63 cap) to keep
// the memory pipeline full at 2-waves/CU structural occupancy.
__global__ __launch_bounds__(64, 1) void ccneuron(
    const float* __restrict__ x,    // [T,B,2]
    const float* __restrict__ cc,   // [T,B,2]
    const float* __restrict__ npx,  // [T,B,2]
    const float* __restrict__ nyx,  // [T,B]
    const float* __restrict__ w_ff, // [B,2]
    const float* __restrict__ w_fb, // [B,2]
    const float* __restrict__ w_lat,// [B,2]
    const float* __restrict__ w_pvl,// [B,2]
    const float* __restrict__ W_pv, // [B,2,2]
    const float* __restrict__ rc,   // [2]
    const float* __restrict__ pv0,  // [B,2]
    const float* __restrict__ y0,   // [B]
    const float* __restrict__ a0,   // [B]
    float* __restrict__ out)        // [T,B,4]
{
    const int b = blockIdx.x * 64 + threadIdx.x;

    const float2 wff  = *(const float2*)(w_ff  + 2 * b);
    const float2 wfb  = *(const float2*)(w_fb  + 2 * b);
    const float2 wlat = *(const float2*)(w_lat + 2 * b);
    const float2 wpvl = *(const float2*)(w_pvl + 2 * b);
    const float4 Wp   = *(const float4*)(W_pv  + 4 * b);  // [p0f0, p0f1, p1f0, p1f1]
    const float r0 = rc[0], r1 = rc[1];
    const float wfbr0 = wfb.x * r0, wfbr1 = wfb.y * r1;

    float2 pv = *(const float2*)(pv0 + 2 * b);
    float  y  = y0[b];
    float  a  = a0[b];

    constexpr int U = 16;
    float2 xA[U], cA[U], nA[U]; float yA[U];
    float2 xB[U], cB[U], nB[U]; float yB[U];

#define LOADBUF(Xb, Cb, Nb, Yb, t0)                                        \
    _Pragma("unroll")                                                      \
    for (int u = 0; u < U; ++u) {                                          \
        int idx = ((t0) + u) * Bn + b;                                     \
        Xb[u] = *(const float2*)(x   + 2 * idx);                           \
        Cb[u] = *(const float2*)(cc  + 2 * idx);                           \
        Nb[u] = *(const float2*)(npx + 2 * idx);                           \
        Yb[u] = nyx[idx];                                                  \
    }

#define COMPBUF(Xb, Cb, Nb, Yb, t0)                                        \
    _Pragma("unroll")                                                      \
    for (int u = 0; u < U; ++u) {                                          \
        /* PV pathway */                                                   \
        float d0 = fmaxf(Wp.x * Xb[u].x + Wp.y * Xb[u].y                   \
                         + y * wpvl.x + Nb[u].x, 0.f);                     \
        float d1 = fmaxf(Wp.z * Xb[u].x + Wp.w * Xb[u].y                   \
                         + y * wpvl.y + Nb[u].y, 0.f);                     \
        float pn0 = 0.25f * d0 + 0.75f * pv.x;                             \
        float pn1 = 0.25f * d1 + 0.75f * pv.y;                             \
        /* adaptation EMA (uses old y) */                                  \
        float an = 0.02f * y + 0.98f * a;                                  \
        /* pyramidal */                                                    \
        float yd = fmaxf(wff.x * Xb[u].x + wff.y * Xb[u].y                 \
                         + wfbr0 * Cb[u].x + wfbr1 * Cb[u].y               \
                         - (wlat.x * pn0 + wlat.y * pn1)                   \
                         + Yb[u] - an, 0.f);                               \
        float yn = 0.1f * yd + 0.9f * y;                                   \
        f32x4 o;                                                           \
        o.x = y; o.y = yn; o.z = pn0; o.w = pn1;                           \
        __builtin_nontemporal_store(o, (f32x4*)(out + 4 * (((t0) + u) * Bn + b))); \
        pv.x = pn0; pv.y = pn1; y = yn; a = an;                            \
    }

    LOADBUF(xA, cA, nA, yA, 0);
    for (int t0 = 0; t0 < Tn; t0 += 2 * U) {
        LOADBUF(xB, cB, nB, yB, t0 + U);
        COMPBUF(xA, cA, nA, yA, t0);
        if (t0 + 2 * U < Tn) {
            LOADBUF(xA, cA, nA, yA, t0 + 2 * U);
        }
        COMPBUF(xB, cB, nB, yB, t0 + U);
    }

#undef LOADBUF
#undef COMPBUF
}

extern "C" void kernel_launch(void* const* d_in, const int* in_sizes, int n_in,
                              void* d_out, int out_size, void* d_ws, size_t ws_size,
                              hipStream_t stream) {
    ccneuron<<<Bn / 64, 64, 0, stream>>>(
        (const float*)d_in[0],   // x
        (const float*)d_in[1],   // c
        (const float*)d_in[2],   // noise_p
        (const float*)d_in[3],   // noise_y
        (const float*)d_in[4],   // w_ff
        (const float*)d_in[5],   // w_fb
        (const float*)d_in[6],   // w_lat
        (const float*)d_in[7],   // w_pv_lat
        (const float*)d_in[8],   // W_pv
        (const float*)d_in[9],   // receives_context
        (const float*)d_in[10],  // pv0
        (const float*)d_in[11],  // y0
        (const float*)d_in[12],  // a0
        (float*)d_out);
}

// Round 4
// 120.119 us; speedup vs baseline: 1.1266x; 1.1266x over previous
//
#include <hip/hip_runtime.h>

#define Tn 512
#define Bn 32768

typedef float f32x4 __attribute__((ext_vector_type(4)));
typedef float f32x2 __attribute__((ext_vector_type(2)));

// One thread per neuron b. Sequential T-loop (carry dependence), double-buffered
// 8-step input prefetch. Noise streams loaded nontemporal so x+c (256 MiB)
// stay L3-resident across graph replays.
__global__ __launch_bounds__(64, 1) void ccneuron(
    const float* __restrict__ x,    // [T,B,2]
    const float* __restrict__ cc,   // [T,B,2]
    const float* __restrict__ npx,  // [T,B,2]
    const float* __restrict__ nyx,  // [T,B]
    const float* __restrict__ w_ff, // [B,2]
    const float* __restrict__ w_fb, // [B,2]
    const float* __restrict__ w_lat,// [B,2]
    const float* __restrict__ w_pvl,// [B,2]
    const float* __restrict__ W_pv, // [B,2,2]
    const float* __restrict__ rc,   // [2]
    const float* __restrict__ pv0,  // [B,2]
    const float* __restrict__ y0,   // [B]
    const float* __restrict__ a0,   // [B]
    float* __restrict__ out)        // [T,B,4]
{
    const int b = blockIdx.x * 64 + threadIdx.x;

    const float2 wff  = *(const float2*)(w_ff  + 2 * b);
    const float2 wfb  = *(const float2*)(w_fb  + 2 * b);
    const float2 wlat = *(const float2*)(w_lat + 2 * b);
    const float2 wpvl = *(const float2*)(w_pvl + 2 * b);
    const float4 Wp   = *(const float4*)(W_pv  + 4 * b);  // [p0f0, p0f1, p1f0, p1f1]
    const float r0 = rc[0], r1 = rc[1];
    const float wfbr0 = wfb.x * r0, wfbr1 = wfb.y * r1;

    float2 pv = *(const float2*)(pv0 + 2 * b);
    float  y  = y0[b];
    float  a  = a0[b];

    constexpr int U = 8;
    float2 xA[U], cA[U]; f32x2 nA[U]; float yA[U];
    float2 xB[U], cB[U]; f32x2 nB[U]; float yB[U];

#define LOADBUF(Xb, Cb, Nb, Yb, t0)                                        \
    _Pragma("unroll")                                                      \
    for (int u = 0; u < U; ++u) {                                          \
        int idx = ((t0) + u) * Bn + b;                                     \
        Xb[u] = *(const float2*)(x   + 2 * idx);                           \
        Cb[u] = *(const float2*)(cc  + 2 * idx);                           \
        Nb[u] = __builtin_nontemporal_load((const f32x2*)(npx + 2 * idx)); \
        Yb[u] = __builtin_nontemporal_load(nyx + idx);                     \
    }

#define COMPBUF(Xb, Cb, Nb, Yb, t0)                                        \
    _Pragma("unroll")                                                      \
    for (int u = 0; u < U; ++u) {                                          \
        /* PV pathway */                                                   \
        float d0 = fmaxf(Wp.x * Xb[u].x + Wp.y * Xb[u].y                   \
                         + y * wpvl.x + Nb[u].x, 0.f);                     \
        float d1 = fmaxf(Wp.z * Xb[u].x + Wp.w * Xb[u].y                   \
                         + y * wpvl.y + Nb[u].y, 0.f);                     \
        float pn0 = 0.25f * d0 + 0.75f * pv.x;                             \
        float pn1 = 0.25f * d1 + 0.75f * pv.y;                             \
        /* adaptation EMA (uses old y) */                                  \
        float an = 0.02f * y + 0.98f * a;                                  \
        /* pyramidal */                                                    \
        float yd = fmaxf(wff.x * Xb[u].x + wff.y * Xb[u].y                 \
                         + wfbr0 * Cb[u].x + wfbr1 * Cb[u].y               \
                         - (wlat.x * pn0 + wlat.y * pn1)                   \
                         + Yb[u] - an, 0.f);                               \
        float yn = 0.1f * yd + 0.9f * y;                                   \
        f32x4 o;                                                           \
        o.x = y; o.y = yn; o.z = pn0; o.w = pn1;                           \
        __builtin_nontemporal_store(o, (f32x4*)(out + 4 * (((t0) + u) * Bn + b))); \
        pv.x = pn0; pv.y = pn1; y = yn; a = an;                            \
    }

    LOADBUF(xA, cA, nA, yA, 0);
    for (int t0 = 0; t0 < Tn; t0 += 2 * U) {
        LOADBUF(xB, cB, nB, yB, t0 + U);
        COMPBUF(xA, cA, nA, yA, t0);
        if (t0 + 2 * U < Tn) {
            LOADBUF(xA, cA, nA, yA, t0 + 2 * U);
        }
        COMPBUF(xB, cB, nB, yB, t0 + U);
    }

#undef LOADBUF
#undef COMPBUF
}

extern "C" void kernel_launch(void* const* d_in, const int* in_sizes, int n_in,
                              void* d_out, int out_size, void* d_ws, size_t ws_size,
                              hipStream_t stream) {
    ccneuron<<<Bn / 64, 64, 0, stream>>>(
        (const float*)d_in[0],   // x
        (const float*)d_in[1],   // c
        (const float*)d_in[2],   // noise_p
        (const float*)d_in[3],   // noise_y
        (const float*)d_in[4],   // w_ff
        (const float*)d_in[5],   // w_fb
        (const float*)d_in[6],   // w_lat
        (const float*)d_in[7],   // w_pv_lat
        (const float*)d_in[8],   // W_pv
        (const float*)d_in[9],   // receives_context
        (const float*)d_in[10],  // pv0
        (const float*)d_in[11],  // y0
        (const float*)d_in[12],  // a0
        (float*)d_out);
}